// Round 8
// baseline (2886.018 us; speedup 1.0000x reference)
//
#include <hip/hip_runtime.h>
#include <math.h>

#define B_ 64
#define T_ 2048
#define E_ 128
#define H_ 128
#define G3_ 384   // 3*H
#define C_ 32
#define M_ (T_ * B_)   // 131072 tokens

typedef _Float16 f16x2 __attribute__((ext_vector_type(2)));

__device__ __forceinline__ f16x2 as_h2(unsigned int u) {
    union { unsigned int u; f16x2 h; } c; c.u = u; return c.h;
}

#if __has_builtin(__builtin_amdgcn_fdot2)
__device__ __forceinline__ float fdot2_acc(f16x2 a, f16x2 b, float c) {
    return __builtin_amdgcn_fdot2(a, b, c, false);
}
#else
__device__ __forceinline__ float fdot2_acc(f16x2 a, f16x2 b, float c) {
    return fmaf((float)a.y, (float)b.y, fmaf((float)a.x, (float)b.x, c));
}
#endif

// ---------------------------------------------------------------------------
// K1: gi[m][r] = bias[r] + dot(w[r][:], emb[x]) ; m = t*B + b  (layer-0 only;
// layer-1 input gates are fused into gru_fused). 384 threads, one output row
// per thread (64 weight VGPRs).
// ---------------------------------------------------------------------------
template <bool GATHER>
__global__ __launch_bounds__(384, 1) void gates_gemm(
    const float* __restrict__ src,   // emb [V,128]
    const int*   __restrict__ xidx,  // x [B,T]
    const float* __restrict__ w,     // [384,128]
    const float* __restrict__ bias,  // [384]
    float* __restrict__ gi)          // [M,384]
{
    const int r = threadIdx.x;  // output row 0..383
    f16x2 wr[64];
    {
        const float2* w2 = (const float2*)(w + (long)r * 128);
#pragma unroll
        for (int i = 0; i < 64; i++) {
            float2 v = w2[i];
            wr[i] = (f16x2){(_Float16)v.x, (_Float16)v.y};
        }
    }
    const float br = bias[r];

    __shared__ __align__(16) f16x2 rows[8][64];   // 8 tokens x 128 f16

    for (int grp = blockIdx.x; grp < M_ / 8; grp += gridDim.x) {
        const int m0 = grp * 8;
        __syncthreads();  // protect rows[] from readers of previous iter
        for (int j = r; j < 512; j += 384) {
            const int s = j >> 6;               // token in group
            const int p = j & 63;               // f16x2 pair within row
            const int mm = m0 + s;
            long row;
            if (GATHER) {
                const int t = mm >> 6;          // m = t*B + b, B=64
                const int bb = mm & 63;
                row = (long)xidx[bb * T_ + t];
            } else {
                row = mm;
            }
            float2 v = ((const float2*)(src + row * 128))[p];
            rows[s][p] = (f16x2){(_Float16)v.x, (_Float16)v.y};
        }
        __syncthreads();
        for (int s = 0; s < 8; s++) {
            const uint4* h16 = (const uint4*)rows[s];
            float a0 = br, a1 = 0.f, a2 = 0.f, a3 = 0.f;
#pragma unroll
            for (int i = 0; i < 16; i++) {
                uint4 u = h16[i];
                a0 = fdot2_acc(wr[4*i+0], as_h2(u.x), a0);
                a1 = fdot2_acc(wr[4*i+1], as_h2(u.y), a1);
                a2 = fdot2_acc(wr[4*i+2], as_h2(u.z), a2);
                a3 = fdot2_acc(wr[4*i+3], as_h2(u.w), a3);
            }
            gi[(long)(m0 + s) * G3_ + r] = (a0 + a1) + (a2 + a3);
        }
    }
}

// ---------------------------------------------------------------------------
// K2: FUSED two-layer GRU recurrence (round 8).
// One block per batch, 768 threads = 12 waves (3/SIMD -> first real TLP).
// Software pipeline: at step s, L0-waves (0..3) compute h0[s] (r7 lane-pair
// K-split, unchanged); L1-waves (4..11) compute h1[s-1] from y0[s-1] (LDS
// f16 ring) and h1[s-2]. 2049 steps total instead of 2*2048 serial.
// L1 folds its input-gate matvec: gh1 = [W_ih1|W_hh1] . [y0; h1], K=256
// split across lane QUADS (kq = idx&3): 3 rows x 64-K window = 96 f16x2
// weight VGPRs/thread (same as L0), 96 dot2. Reduce: shfl_xor(1) combines
// the two K-windows of the same part; shfl_xor(2) exchanges i-part/h-part
// (kept separate: torch GRU n-gate is inn + r*(hn+b_hh_n)).
// Eliminates: 2nd gru dispatch (serial 1110 us), gates_gemm<false>
// (~250 us), 400 MB gi1 HBM traffic, y0 global round-trip.
// LDS: h vectors as 2 x 64-f16 windows, window stride 160 B -> the 4
// concurrent broadcast windows of an L1 wave land on distinct bank phases.
// One raw s_barrier per step, lgkmcnt-only drain; gi0 prefetched 2 steps.
// ---------------------------------------------------------------------------
#define HB0(S) (lds + (S) * 320)
#define Y0R(S) (lds + 640 + (S) * 320)
#define HB1(S) (lds + 1280 + (S) * 320)

#define DOT96(HSRC, S0, S1, S2)                                                \
  {                                                                            \
    float a00 = 0.f, a01 = 0.f, a10 = 0.f, a11 = 0.f, a20 = 0.f, a21 = 0.f;    \
    _Pragma("unroll")                                                          \
    for (int i = 0; i < 8; i++) {                                              \
      uint4 u = (HSRC)[i];                                                     \
      f16x2 ux = as_h2(u.x), uy = as_h2(u.y), uz = as_h2(u.z), uw = as_h2(u.w);\
      a00 = fdot2_acc(wr[0][4*i+0], ux, a00);                                  \
      a10 = fdot2_acc(wr[1][4*i+0], ux, a10);                                  \
      a20 = fdot2_acc(wr[2][4*i+0], ux, a20);                                  \
      a01 = fdot2_acc(wr[0][4*i+1], uy, a01);                                  \
      a11 = fdot2_acc(wr[1][4*i+1], uy, a11);                                  \
      a21 = fdot2_acc(wr[2][4*i+1], uy, a21);                                  \
      a00 = fdot2_acc(wr[0][4*i+2], uz, a00);                                  \
      a10 = fdot2_acc(wr[1][4*i+2], uz, a10);                                  \
      a20 = fdot2_acc(wr[2][4*i+2], uz, a20);                                  \
      a01 = fdot2_acc(wr[0][4*i+3], uw, a01);                                  \
      a11 = fdot2_acc(wr[1][4*i+3], uw, a11);                                  \
      a21 = fdot2_acc(wr[2][4*i+3], uw, a21);                                  \
    }                                                                          \
    S0 = a00 + a01; S1 = a10 + a11; S2 = a20 + a21;                            \
  }

#define FSTEP(SP, TT, IR, IZ, INN)                                             \
  {                                                                            \
    if (isL0) {                                                                \
      if ((TT) < T_) {                                                         \
        const uint4* hsrc = (const uint4*)(HB0(SP) + ksel * 160);              \
        float s0, s1, s2;                                                      \
        DOT96(hsrc, s0, s1, s2);                                               \
        const float hr = s0 + __shfl_xor(s0, 1) + c0;                          \
        const float hz = s1 + __shfl_xor(s1, 1) + c1;                          \
        const float hn = s2 + __shfl_xor(s2, 1) + cn_h;                        \
        const float rr = 1.f / (1.f + __expf(-((IR) + hr)));                   \
        const float zz = 1.f / (1.f + __expf(-((IZ) + hz)));                   \
        const float na = (INN) + rr * hn;                                      \
        const float nn = 1.f - 2.f / (__expf(2.f * na) + 1.f);                 \
        h_own = (1.f - zz) * nn + zz * h_own;                                  \
        char* wb = (ksel == 0) ? HB0((SP) ^ 1) : Y0R(SP);                      \
        *(_Float16*)(wb + ((g >> 6) * 160) + ((g & 63) * 2)) = (_Float16)h_own;\
        const int tp = ((TT) + 2 < T_) ? (TT) + 2 : (TT);                      \
        const float* gp = gi_g + (size_t)tp * (B_ * G3_);                      \
        IR = gp[0]; IZ = gp[128]; INN = gp[256];                               \
      }                                                                        \
    } else {                                                                   \
      if ((TT) > 0) {                                                          \
        const char* base = (ksel < 2) ? Y0R((SP) ^ 1) : HB1(SP);               \
        const uint4* hsrc = (const uint4*)(base + (ksel & 1) * 160);           \
        float s0, s1, s2;                                                      \
        DOT96(hsrc, s0, s1, s2);                                               \
        const float u0 = s0 + __shfl_xor(s0, 1);                               \
        const float u1 = s1 + __shfl_xor(s1, 1);                               \
        const float u2 = s2 + __shfl_xor(s2, 1);                               \
        const float v0 = __shfl_xor(u0, 2);                                    \
        const float v1 = __shfl_xor(u1, 2);                                    \
        const float v2 = __shfl_xor(u2, 2);                                    \
        const float rr = 1.f / (1.f + __expf(-(u0 + v0 + c0)));                \
        const float zz = 1.f / (1.f + __expf(-(u1 + v1 + c1)));                \
        const float inn = (ksel < 2) ? u2 : v2;                                \
        const float hnn = (ksel < 2) ? v2 : u2;                                \
        const float na = inn + cn_i + rr * (hnn + cn_h);                       \
        const float nn = 1.f - 2.f / (__expf(2.f * na) + 1.f);                 \
        h_own = (1.f - zz) * nn + zz * h_own;                                  \
        if (ksel == 0)                                                         \
          *(_Float16*)(HB1((SP) ^ 1) + ((g >> 6) * 160) + ((g & 63) * 2)) =    \
              (_Float16)h_own;                                                 \
        if (ksel == 1)                                                         \
          y[((size_t)((TT) - 1) * B_ + b) * H_ + g] = h_own;                   \
      }                                                                        \
    }                                                                          \
    asm volatile("s_waitcnt lgkmcnt(0)" ::: "memory");                         \
    __builtin_amdgcn_s_barrier();                                              \
    __builtin_amdgcn_sched_barrier(0);                                         \
  }

__global__ __launch_bounds__(768, 3) void gru_fused(
    const float* __restrict__ gi,     // [M,384]  layer-0 input gates
    const float* __restrict__ w_hh0,  // [384,128]
    const float* __restrict__ b_hh0,  // [384]
    const float* __restrict__ w_ih1,  // [384,128]
    const float* __restrict__ w_hh1,  // [384,128]
    const float* __restrict__ b_ih1,  // [384]
    const float* __restrict__ b_hh1,  // [384]
    float* __restrict__ y)            // [M,128]  layer-1 output (t*B+b major)
{
    const int tid = threadIdx.x;
    const int wv  = tid >> 6;
    const int l   = tid & 63;
    const int b   = blockIdx.x;
    const bool isL0 = (wv < 4);

    int g, ksel;
    const float* wsrc;
    if (isL0) {
        g = wv * 32 + (l >> 1);      // h0-dim (pair-shared)
        ksel = l & 1;                // K-half of h0
        wsrc = w_hh0;
    } else {
        const int idx = (wv - 4) * 64 + l;   // 0..511
        g = idx >> 2;                // h1-dim (quad-shared)
        ksel = idx & 3;              // quad: 0,1 = y0-part; 2,3 = h1-part
        wsrc = (ksel < 2) ? w_ih1 : w_hh1;
    }
    const int kwin = (isL0 ? ksel : (ksel & 1)) * 64;

    // weights: rows {g, g+128, g+256}, K-window [kwin, kwin+64)
    f16x2 wr[3][32];
#pragma unroll
    for (int G = 0; G < 3; G++) {
        const float2* w2 = (const float2*)(wsrc + (size_t)(g + 128 * G) * 128 + kwin);
#pragma unroll
        for (int i = 0; i < 32; i++) {
            float2 v = w2[i];
            wr[G][i] = (f16x2){(_Float16)v.x, (_Float16)v.y};
        }
    }
    // biases: L0: c0,c1 = b_hh0 r/z; cn_h = b_hh0 n (gi already has b_ih0).
    //         L1: c0,c1 = b_ih1+b_hh1 r/z; cn_i = b_ih1 n; cn_h = b_hh1 n.
    float c0, c1, cn_i, cn_h;
    if (isL0) {
        c0 = b_hh0[g]; c1 = b_hh0[g + 128]; cn_i = 0.f; cn_h = b_hh0[g + 256];
    } else {
        c0 = b_ih1[g] + b_hh1[g];
        c1 = b_ih1[g + 128] + b_hh1[g + 128];
        cn_i = b_ih1[g + 256];
        cn_h = b_hh1[g + 256];
    }

    // LDS: hb0[2] | y0ring[2] | hb1[2]; each slot = 2 windows x 160 B
    __shared__ __align__(16) char lds[1920];
    if (tid < 120) ((uint4*)lds)[tid] = (uint4){0, 0, 0, 0};

    float h_own = 0.f;

    const float* gi_g = gi + (size_t)b * G3_ + g;

    // gi0 prefetch (L0 only): t=0 -> A set, t=1 -> B set
    float irA = 0.f, izA = 0.f, innA = 0.f, irB = 0.f, izB = 0.f, innB = 0.f;
    if (isL0) {
        irA = gi_g[0]; izA = gi_g[128]; innA = gi_g[256];
        const float* p1 = gi_g + (size_t)(B_ * G3_);
        irB = p1[0]; izB = p1[128]; innB = p1[256];
    }

    __syncthreads();  // one-time full drain: LDS zero-init visible

    for (int t = 0; t < T_; t += 2) {
        FSTEP(0, t,     irA, izA, innA)
        FSTEP(1, t + 1, irB, izB, innB)
    }
    FSTEP(0, T_, irA, izA, innA)   // step 2048: L0 idle, L1 finishes h1[2047]
}

// ---------------------------------------------------------------------------
// K5: out[b*T+t][c] = relu(fc_b[c] + dot(fc_w[c], y[t*B+b]))
// ---------------------------------------------------------------------------
__global__ __launch_bounds__(256, 2) void fc_relu(
    const float* __restrict__ y,     // [M,128]
    const float* __restrict__ fc_w,  // [32,128]
    const float* __restrict__ fc_b,  // [32]
    float* __restrict__ out)         // [B*T,32]
{
    const int tid = threadIdx.x;
    const int c = tid & 31;
    const int slot = tid >> 5;

    float4 wr[32];
    const float4* w4 = (const float4*)(fc_w + c * 128);
#pragma unroll
    for (int i = 0; i < 32; i++) wr[i] = w4[i];
    const float bc = fc_b[c];

    __shared__ __align__(16) float rows[8][128];

    for (int grp = blockIdx.x; grp < M_ / 8; grp += gridDim.x) {
        const int m0 = grp * 8;
        __syncthreads();
        for (int i = tid; i < 8 * 128; i += 256) {
            rows[i >> 7][i & 127] = y[(long)m0 * 128 + i];
        }
        __syncthreads();
        const float4* h4 = (const float4*)rows[slot];
        float a0 = bc, a1 = 0.f, a2 = 0.f, a3 = 0.f;
#pragma unroll
        for (int i = 0; i < 32; i += 4) {
            float4 h0 = h4[i], h1 = h4[i + 1], h2 = h4[i + 2], h3 = h4[i + 3];
            a0 = fmaf(wr[i].w, h0.w, fmaf(wr[i].z, h0.z, fmaf(wr[i].y, h0.y, fmaf(wr[i].x, h0.x, a0))));
            a1 = fmaf(wr[i+1].w, h1.w, fmaf(wr[i+1].z, h1.z, fmaf(wr[i+1].y, h1.y, fmaf(wr[i+1].x, h1.x, a1))));
            a2 = fmaf(wr[i+2].w, h2.w, fmaf(wr[i+2].z, h2.z, fmaf(wr[i+2].y, h2.y, fmaf(wr[i+2].x, h2.x, a2))));
            a3 = fmaf(wr[i+3].w, h3.w, fmaf(wr[i+3].z, h3.z, fmaf(wr[i+3].y, h3.y, fmaf(wr[i+3].x, h3.x, a3))));
        }
        float acc = (a0 + a1) + (a2 + a3);
        acc = fmaxf(acc, 0.f);
        const int m = m0 + slot;
        const int t = m >> 6;
        const int b = m & 63;
        out[((long)b * T_ + t) * C_ + c] = acc;
    }
}

// ---------------------------------------------------------------------------
extern "C" void kernel_launch(void* const* d_in, const int* in_sizes, int n_in,
                              void* d_out, int out_size, void* d_ws, size_t ws_size,
                              hipStream_t stream) {
    const int*   x     = (const int*)d_in[0];
    const float* emb   = (const float*)d_in[1];
    const float* w_ih0 = (const float*)d_in[2];
    const float* w_hh0 = (const float*)d_in[3];
    const float* b_ih0 = (const float*)d_in[4];
    const float* b_hh0 = (const float*)d_in[5];
    const float* w_ih1 = (const float*)d_in[6];
    const float* w_hh1 = (const float*)d_in[7];
    const float* b_ih1 = (const float*)d_in[8];
    const float* b_hh1 = (const float*)d_in[9];
    const float* fc_w  = (const float*)d_in[10];
    const float* fc_b  = (const float*)d_in[11];
    float* out = (float*)d_out;

    // workspace: gi0 [M,384] fp32 (201.3 MB) + y1 [M,128] fp32 (67.1 MB)
    float* gi = (float*)d_ws;
    float* yb = (float*)((char*)d_ws + (size_t)M_ * G3_ * sizeof(float));

    // layer 0 input gates (embedding gather fused)
    gates_gemm<true><<<512, 384, 0, stream>>>(emb, x, w_ih0, b_ih0, gi);
    // FUSED: layer-0 recurrence + layer-1 input gates + layer-1 recurrence
    gru_fused<<<B_, 768, 0, stream>>>(gi, w_hh0, b_hh0, w_ih1, w_hh1, b_ih1, b_hh1, yb);
    // FC + ReLU
    fc_relu<<<512, 256, 0, stream>>>(yb, fc_w, fc_b, out);
}

// Round 9
// 2885.142 us; speedup vs baseline: 1.0003x; 1.0003x over previous
//
#include <hip/hip_runtime.h>
#include <math.h>

#define B_ 64
#define T_ 2048
#define E_ 128
#define H_ 128
#define G3_ 384   // 3*H
#define C_ 32
#define M_ (T_ * B_)   // 131072 tokens

typedef _Float16 f16x2 __attribute__((ext_vector_type(2)));

__device__ __forceinline__ f16x2 as_h2(unsigned int u) {
    union { unsigned int u; f16x2 h; } c; c.u = u; return c.h;
}

#if __has_builtin(__builtin_amdgcn_fdot2)
__device__ __forceinline__ float fdot2_acc(f16x2 a, f16x2 b, float c) {
    return __builtin_amdgcn_fdot2(a, b, c, false);
}
#else
__device__ __forceinline__ float fdot2_acc(f16x2 a, f16x2 b, float c) {
    return fmaf((float)a.y, (float)b.y, fmaf((float)a.x, (float)b.x, c));
}
#endif

// ---------------------------------------------------------------------------
// K1: gi[m][r] = bias[r] + dot(w[r][:], emb[x]) ; m = t*B + b  (layer-0 only;
// layer-1 input gates are fused into gru_fused). 384 threads, one output row
// per thread (64 weight VGPRs).
// ---------------------------------------------------------------------------
template <bool GATHER>
__global__ __launch_bounds__(384, 1) void gates_gemm(
    const float* __restrict__ src,   // emb [V,128]
    const int*   __restrict__ xidx,  // x [B,T]
    const float* __restrict__ w,     // [384,128]
    const float* __restrict__ bias,  // [384]
    float* __restrict__ gi)          // [M,384]
{
    const int r = threadIdx.x;  // output row 0..383
    f16x2 wr[64];
    {
        const float2* w2 = (const float2*)(w + (long)r * 128);
#pragma unroll
        for (int i = 0; i < 64; i++) {
            float2 v = w2[i];
            wr[i] = (f16x2){(_Float16)v.x, (_Float16)v.y};
        }
    }
    const float br = bias[r];

    __shared__ __align__(16) f16x2 rows[8][64];   // 8 tokens x 128 f16

    for (int grp = blockIdx.x; grp < M_ / 8; grp += gridDim.x) {
        const int m0 = grp * 8;
        __syncthreads();  // protect rows[] from readers of previous iter
        for (int j = r; j < 512; j += 384) {
            const int s = j >> 6;               // token in group
            const int p = j & 63;               // f16x2 pair within row
            const int mm = m0 + s;
            long row;
            if (GATHER) {
                const int t = mm >> 6;          // m = t*B + b, B=64
                const int bb = mm & 63;
                row = (long)xidx[bb * T_ + t];
            } else {
                row = mm;
            }
            float2 v = ((const float2*)(src + row * 128))[p];
            rows[s][p] = (f16x2){(_Float16)v.x, (_Float16)v.y};
        }
        __syncthreads();
        for (int s = 0; s < 8; s++) {
            const uint4* h16 = (const uint4*)rows[s];
            float a0 = br, a1 = 0.f, a2 = 0.f, a3 = 0.f;
#pragma unroll
            for (int i = 0; i < 16; i++) {
                uint4 u = h16[i];
                a0 = fdot2_acc(wr[4*i+0], as_h2(u.x), a0);
                a1 = fdot2_acc(wr[4*i+1], as_h2(u.y), a1);
                a2 = fdot2_acc(wr[4*i+2], as_h2(u.z), a2);
                a3 = fdot2_acc(wr[4*i+3], as_h2(u.w), a3);
            }
            gi[(long)(m0 + s) * G3_ + r] = (a0 + a1) + (a2 + a3);
        }
    }
}

// ---------------------------------------------------------------------------
// K2: FUSED two-layer GRU recurrence.
// One block per batch, 768 threads = 12 waves (3/SIMD).
// Round-9 change: amdgpu_waves_per_eu(3,3) pins occupancy so the register
// allocator gets the full 512/3 = 170-VGPR budget. Round 8's
// __launch_bounds__(768,3) only set a MINIMUM; the compiler shrank to 84
// VGPRs (= the 6-wave/SIMD budget 85) and spilled ~60 weight values to
// scratch — WRITE_SIZE +11.9 MB (= 64x768x~242 B spill slots) and ~60
// scratch reloads/thread/step were the 2935-cyc/step cost. Everything else
// identical to round 8.
// ---------------------------------------------------------------------------
#define HB0(S) (lds + (S) * 320)
#define Y0R(S) (lds + 640 + (S) * 320)
#define HB1(S) (lds + 1280 + (S) * 320)

#define DOT96(HSRC, S0, S1, S2)                                                \
  {                                                                            \
    float a00 = 0.f, a01 = 0.f, a10 = 0.f, a11 = 0.f, a20 = 0.f, a21 = 0.f;    \
    _Pragma("unroll")                                                          \
    for (int i = 0; i < 8; i++) {                                              \
      uint4 u = (HSRC)[i];                                                     \
      f16x2 ux = as_h2(u.x), uy = as_h2(u.y), uz = as_h2(u.z), uw = as_h2(u.w);\
      a00 = fdot2_acc(wr[0][4*i+0], ux, a00);                                  \
      a10 = fdot2_acc(wr[1][4*i+0], ux, a10);                                  \
      a20 = fdot2_acc(wr[2][4*i+0], ux, a20);                                  \
      a01 = fdot2_acc(wr[0][4*i+1], uy, a01);                                  \
      a11 = fdot2_acc(wr[1][4*i+1], uy, a11);                                  \
      a21 = fdot2_acc(wr[2][4*i+1], uy, a21);                                  \
      a00 = fdot2_acc(wr[0][4*i+2], uz, a00);                                  \
      a10 = fdot2_acc(wr[1][4*i+2], uz, a10);                                  \
      a20 = fdot2_acc(wr[2][4*i+2], uz, a20);                                  \
      a01 = fdot2_acc(wr[0][4*i+3], uw, a01);                                  \
      a11 = fdot2_acc(wr[1][4*i+3], uw, a11);                                  \
      a21 = fdot2_acc(wr[2][4*i+3], uw, a21);                                  \
    }                                                                          \
    S0 = a00 + a01; S1 = a10 + a11; S2 = a20 + a21;                            \
  }

#define FSTEP(SP, TT, IR, IZ, INN)                                             \
  {                                                                            \
    if (isL0) {                                                                \
      if ((TT) < T_) {                                                         \
        const uint4* hsrc = (const uint4*)(HB0(SP) + ksel * 160);              \
        float s0, s1, s2;                                                      \
        DOT96(hsrc, s0, s1, s2);                                               \
        const float hr = s0 + __shfl_xor(s0, 1) + c0;                          \
        const float hz = s1 + __shfl_xor(s1, 1) + c1;                          \
        const float hn = s2 + __shfl_xor(s2, 1) + cn_h;                        \
        const float rr = 1.f / (1.f + __expf(-((IR) + hr)));                   \
        const float zz = 1.f / (1.f + __expf(-((IZ) + hz)));                   \
        const float na = (INN) + rr * hn;                                      \
        const float nn = 1.f - 2.f / (__expf(2.f * na) + 1.f);                 \
        h_own = (1.f - zz) * nn + zz * h_own;                                  \
        char* wb = (ksel == 0) ? HB0((SP) ^ 1) : Y0R(SP);                      \
        *(_Float16*)(wb + ((g >> 6) * 160) + ((g & 63) * 2)) = (_Float16)h_own;\
        const int tp = ((TT) + 2 < T_) ? (TT) + 2 : (TT);                      \
        const float* gp = gi_g + (size_t)tp * (B_ * G3_);                      \
        IR = gp[0]; IZ = gp[128]; INN = gp[256];                               \
      }                                                                        \
    } else {                                                                   \
      if ((TT) > 0) {                                                          \
        const char* base = (ksel < 2) ? Y0R((SP) ^ 1) : HB1(SP);               \
        const uint4* hsrc = (const uint4*)(base + (ksel & 1) * 160);           \
        float s0, s1, s2;                                                      \
        DOT96(hsrc, s0, s1, s2);                                               \
        const float u0 = s0 + __shfl_xor(s0, 1);                               \
        const float u1 = s1 + __shfl_xor(s1, 1);                               \
        const float u2 = s2 + __shfl_xor(s2, 1);                               \
        const float v0 = __shfl_xor(u0, 2);                                    \
        const float v1 = __shfl_xor(u1, 2);                                    \
        const float v2 = __shfl_xor(u2, 2);                                    \
        const float rr = 1.f / (1.f + __expf(-(u0 + v0 + c0)));                \
        const float zz = 1.f / (1.f + __expf(-(u1 + v1 + c1)));                \
        const float inn = (ksel < 2) ? u2 : v2;                                \
        const float hnn = (ksel < 2) ? v2 : u2;                                \
        const float na = inn + cn_i + rr * (hnn + cn_h);                       \
        const float nn = 1.f - 2.f / (__expf(2.f * na) + 1.f);                 \
        h_own = (1.f - zz) * nn + zz * h_own;                                  \
        if (ksel == 0)                                                         \
          *(_Float16*)(HB1((SP) ^ 1) + ((g >> 6) * 160) + ((g & 63) * 2)) =    \
              (_Float16)h_own;                                                 \
        if (ksel == 1)                                                         \
          y[((size_t)((TT) - 1) * B_ + b) * H_ + g] = h_own;                   \
      }                                                                        \
    }                                                                          \
    asm volatile("s_waitcnt lgkmcnt(0)" ::: "memory");                         \
    __builtin_amdgcn_s_barrier();                                              \
    __builtin_amdgcn_sched_barrier(0);                                         \
  }

__global__ __attribute__((amdgpu_flat_work_group_size(768, 768)))
__attribute__((amdgpu_waves_per_eu(3, 3))) void gru_fused(
    const float* __restrict__ gi,     // [M,384]  layer-0 input gates
    const float* __restrict__ w_hh0,  // [384,128]
    const float* __restrict__ b_hh0,  // [384]
    const float* __restrict__ w_ih1,  // [384,128]
    const float* __restrict__ w_hh1,  // [384,128]
    const float* __restrict__ b_ih1,  // [384]
    const float* __restrict__ b_hh1,  // [384]
    float* __restrict__ y)            // [M,128]  layer-1 output (t*B+b major)
{
    const int tid = threadIdx.x;
    const int wv  = tid >> 6;
    const int l   = tid & 63;
    const int b   = blockIdx.x;
    const bool isL0 = (wv < 4);

    int g, ksel;
    const float* wsrc;
    if (isL0) {
        g = wv * 32 + (l >> 1);      // h0-dim (pair-shared)
        ksel = l & 1;                // K-half of h0
        wsrc = w_hh0;
    } else {
        const int idx = (wv - 4) * 64 + l;   // 0..511
        g = idx >> 2;                // h1-dim (quad-shared)
        ksel = idx & 3;              // quad: 0,1 = y0-part; 2,3 = h1-part
        wsrc = (ksel < 2) ? w_ih1 : w_hh1;
    }
    const int kwin = (isL0 ? ksel : (ksel & 1)) * 64;

    // weights: rows {g, g+128, g+256}, K-window [kwin, kwin+64)
    f16x2 wr[3][32];
#pragma unroll
    for (int G = 0; G < 3; G++) {
        const float2* w2 = (const float2*)(wsrc + (size_t)(g + 128 * G) * 128 + kwin);
#pragma unroll
        for (int i = 0; i < 32; i++) {
            float2 v = w2[i];
            wr[G][i] = (f16x2){(_Float16)v.x, (_Float16)v.y};
        }
    }
    // biases: L0: c0,c1 = b_hh0 r/z; cn_h = b_hh0 n (gi already has b_ih0).
    //         L1: c0,c1 = b_ih1+b_hh1 r/z; cn_i = b_ih1 n; cn_h = b_hh1 n.
    float c0, c1, cn_i, cn_h;
    if (isL0) {
        c0 = b_hh0[g]; c1 = b_hh0[g + 128]; cn_i = 0.f; cn_h = b_hh0[g + 256];
    } else {
        c0 = b_ih1[g] + b_hh1[g];
        c1 = b_ih1[g + 128] + b_hh1[g + 128];
        cn_i = b_ih1[g + 256];
        cn_h = b_hh1[g + 256];
    }

    // LDS: hb0[2] | y0ring[2] | hb1[2]; each slot = 2 windows x 160 B
    __shared__ __align__(16) char lds[1920];
    if (tid < 120) ((uint4*)lds)[tid] = (uint4){0, 0, 0, 0};

    float h_own = 0.f;

    const float* gi_g = gi + (size_t)b * G3_ + g;

    // gi0 prefetch (L0 only): t=0 -> A set, t=1 -> B set
    float irA = 0.f, izA = 0.f, innA = 0.f, irB = 0.f, izB = 0.f, innB = 0.f;
    if (isL0) {
        irA = gi_g[0]; izA = gi_g[128]; innA = gi_g[256];
        const float* p1 = gi_g + (size_t)(B_ * G3_);
        irB = p1[0]; izB = p1[128]; innB = p1[256];
    }

    __syncthreads();  // one-time full drain: LDS zero-init visible

    for (int t = 0; t < T_; t += 2) {
        FSTEP(0, t,     irA, izA, innA)
        FSTEP(1, t + 1, irB, izB, innB)
    }
    FSTEP(0, T_, irA, izA, innA)   // step 2048: L0 idle, L1 finishes h1[2047]
}

// ---------------------------------------------------------------------------
// K5: out[b*T+t][c] = relu(fc_b[c] + dot(fc_w[c], y[t*B+b]))
// ---------------------------------------------------------------------------
__global__ __launch_bounds__(256, 2) void fc_relu(
    const float* __restrict__ y,     // [M,128]
    const float* __restrict__ fc_w,  // [32,128]
    const float* __restrict__ fc_b,  // [32]
    float* __restrict__ out)         // [B*T,32]
{
    const int tid = threadIdx.x;
    const int c = tid & 31;
    const int slot = tid >> 5;

    float4 wr[32];
    const float4* w4 = (const float4*)(fc_w + c * 128);
#pragma unroll
    for (int i = 0; i < 32; i++) wr[i] = w4[i];
    const float bc = fc_b[c];

    __shared__ __align__(16) float rows[8][128];

    for (int grp = blockIdx.x; grp < M_ / 8; grp += gridDim.x) {
        const int m0 = grp * 8;
        __syncthreads();
        for (int i = tid; i < 8 * 128; i += 256) {
            rows[i >> 7][i & 127] = y[(long)m0 * 128 + i];
        }
        __syncthreads();
        const float4* h4 = (const float4*)rows[slot];
        float a0 = bc, a1 = 0.f, a2 = 0.f, a3 = 0.f;
#pragma unroll
        for (int i = 0; i < 32; i += 4) {
            float4 h0 = h4[i], h1 = h4[i + 1], h2 = h4[i + 2], h3 = h4[i + 3];
            a0 = fmaf(wr[i].w, h0.w, fmaf(wr[i].z, h0.z, fmaf(wr[i].y, h0.y, fmaf(wr[i].x, h0.x, a0))));
            a1 = fmaf(wr[i+1].w, h1.w, fmaf(wr[i+1].z, h1.z, fmaf(wr[i+1].y, h1.y, fmaf(wr[i+1].x, h1.x, a1))));
            a2 = fmaf(wr[i+2].w, h2.w, fmaf(wr[i+2].z, h2.z, fmaf(wr[i+2].y, h2.y, fmaf(wr[i+2].x, h2.x, a2))));
            a3 = fmaf(wr[i+3].w, h3.w, fmaf(wr[i+3].z, h3.z, fmaf(wr[i+3].y, h3.y, fmaf(wr[i+3].x, h3.x, a3))));
        }
        float acc = (a0 + a1) + (a2 + a3);
        acc = fmaxf(acc, 0.f);
        const int m = m0 + slot;
        const int t = m >> 6;
        const int b = m & 63;
        out[((long)b * T_ + t) * C_ + c] = acc;
    }
}

// ---------------------------------------------------------------------------
extern "C" void kernel_launch(void* const* d_in, const int* in_sizes, int n_in,
                              void* d_out, int out_size, void* d_ws, size_t ws_size,
                              hipStream_t stream) {
    const int*   x     = (const int*)d_in[0];
    const float* emb   = (const float*)d_in[1];
    const float* w_ih0 = (const float*)d_in[2];
    const float* w_hh0 = (const float*)d_in[3];
    const float* b_ih0 = (const float*)d_in[4];
    const float* b_hh0 = (const float*)d_in[5];
    const float* w_ih1 = (const float*)d_in[6];
    const float* w_hh1 = (const float*)d_in[7];
    const float* b_ih1 = (const float*)d_in[8];
    const float* b_hh1 = (const float*)d_in[9];
    const float* fc_w  = (const float*)d_in[10];
    const float* fc_b  = (const float*)d_in[11];
    float* out = (float*)d_out;

    // workspace: gi0 [M,384] fp32 (201.3 MB) + y1 [M,128] fp32 (67.1 MB)
    float* gi = (float*)d_ws;
    float* yb = (float*)((char*)d_ws + (size_t)M_ * G3_ * sizeof(float));

    // layer 0 input gates (embedding gather fused)
    gates_gemm<true><<<512, 384, 0, stream>>>(emb, x, w_ih0, b_ih0, gi);
    // FUSED: layer-0 recurrence + layer-1 input gates + layer-1 recurrence
    gru_fused<<<B_, 768, 0, stream>>>(gi, w_hh0, b_hh0, w_ih1, w_hh1, b_ih1, b_hh1, yb);
    // FC + ReLU
    fc_relu<<<512, 256, 0, stream>>>(yb, fc_w, fc_b, out);
}